// Round 8
// baseline (167.895 us; speedup 1.0000x reference)
//
#include <hip/hip_runtime.h>
#include <hip/hip_bf16.h>

#define NB 1024
#define SS 256
#define LL 256
#define HH 128
#define KMAX 16
#define KE 8

typedef __attribute__((ext_vector_type(8))) short bf16x8;
typedef __attribute__((ext_vector_type(4))) float f32x4;
typedef unsigned short u16;
typedef unsigned int u32;

__device__ __forceinline__ void split_bf16(float a, u16& hi, u16& lo) {
  u32 u = __float_as_uint(a);
  u32 hb = (u + 0x8000u) & 0xFFFF0000u;      // RTN-ish bf16 hi
  float lf = a - __uint_as_float(hb);        // exact residual
  hi = (u16)(hb >> 16);
  lo = (u16)(__float_as_uint(lf) >> 16);
}

// ---- prep: W[l][h] -> Wt_hi[h][l], Wt_lo[h][l] (bf16 split, transposed) ----
__global__ __launch_bounds__(256) void prep_w(
    const float* __restrict__ Wm, u16* __restrict__ wt_hi, u16* __restrict__ wt_lo) {
  const int id = blockIdx.x * 256 + threadIdx.x;
  const int h = id & 127, l = id >> 7;
  const float a = Wm[(size_t)l * HH + h];
  u16 hi, lo;
  split_bf16(a, hi, lo);
  wt_hi[h * LL + l] = hi;
  wt_lo[h * LL + l] = lo;
}

// ============== Kernel 1: MFMA GEMM, split-bf16, reg-prefetch ==============
#define BM 128
#define BK 32
#define APAD 40

__global__ __launch_bounds__(256, 3) void gemm_mfma(
    const float* __restrict__ inputs, const int* __restrict__ seq_len,
    const u16* __restrict__ wt_hi, const u16* __restrict__ wt_lo,
    float* __restrict__ lowbuf) {
  __shared__ u16 Ahi[BM][APAD], Alo[BM][APAD];
  __shared__ u16 Bhi[HH][APAD], Blo[HH][APAD];

  const int bid = blockIdx.x;
  const int batch = bid >> 1;
  const int r0 = (bid & 1) * BM;
  const int sl = seq_len[batch];
  if (r0 >= sl) return;

  const int t = threadIdx.x;
  const int w = t >> 6;
  const int l = t & 63;
  const int lr = l & 15;
  const int lk = l >> 4;

  f32x4 acc[2][8];
  #pragma unroll
  for (int mt = 0; mt < 2; ++mt)
    #pragma unroll
    for (int nt = 0; nt < 8; ++nt) acc[mt][nt] = (f32x4){0.f, 0.f, 0.f, 0.f};

  const float* Ab = inputs + ((size_t)batch * SS + r0) * LL;
  const int bh = t >> 1, be = t & 1;
  const bool wave_active = (r0 + w * 32) < sl;
  const int arow = t >> 3, aq = t & 7;           // this thread's A-stage coords

  // prefetch registers for the A tile (4 float4 per thread)
  float4 pre0, pre1, pre2, pre3;
  {
    const int kc = 0;
    if (r0 + arow < sl)        pre0 = *(const float4*)(Ab + (size_t)arow * LL + kc + aq * 4);
    if (r0 + arow + 32 < sl)   pre1 = *(const float4*)(Ab + (size_t)(arow + 32) * LL + kc + aq * 4);
    if (r0 + arow + 64 < sl)   pre2 = *(const float4*)(Ab + (size_t)(arow + 64) * LL + kc + aq * 4);
    if (r0 + arow + 96 < sl)   pre3 = *(const float4*)(Ab + (size_t)(arow + 96) * LL + kc + aq * 4);
  }

  for (int kc = 0; kc < LL; kc += BK) {
    // ---- consume prefetched A: split -> LDS ----
    #pragma unroll
    for (int m = 0; m < 4; ++m) {
      const int row = arow + m * 32;
      const float4 v = (m == 0) ? pre0 : (m == 1) ? pre1 : (m == 2) ? pre2 : pre3;
      if (r0 + row < sl) {
        u16 h0,h1,h2,h3, l0,l1,l2,l3;
        split_bf16(v.x, h0, l0); split_bf16(v.y, h1, l1);
        split_bf16(v.z, h2, l2); split_bf16(v.w, h3, l3);
        uint2 hp, lp;
        hp.x = (u32)h0 | ((u32)h1 << 16);  hp.y = (u32)h2 | ((u32)h3 << 16);
        lp.x = (u32)l0 | ((u32)l1 << 16);  lp.y = (u32)l2 | ((u32)l3 << 16);
        *(uint2*)&Ahi[row][aq * 4] = hp;
        *(uint2*)&Alo[row][aq * 4] = lp;
      }
    }
    // ---- stage B ----
    {
      const u16* sh = wt_hi + (size_t)bh * LL + kc + be * 16;
      const u16* sv = wt_lo + (size_t)bh * LL + kc + be * 16;
      *(uint4*)&Bhi[bh][be * 16]     = *(const uint4*)(sh);
      *(uint4*)&Bhi[bh][be * 16 + 8] = *(const uint4*)(sh + 8);
      *(uint4*)&Blo[bh][be * 16]     = *(const uint4*)(sv);
      *(uint4*)&Blo[bh][be * 16 + 8] = *(const uint4*)(sv + 8);
    }
    // ---- issue next-tile A loads (hide HBM latency under barriers+MFMA) ----
    if (kc + BK < LL) {
      const int kn = kc + BK;
      if (r0 + arow < sl)        pre0 = *(const float4*)(Ab + (size_t)arow * LL + kn + aq * 4);
      if (r0 + arow + 32 < sl)   pre1 = *(const float4*)(Ab + (size_t)(arow + 32) * LL + kn + aq * 4);
      if (r0 + arow + 64 < sl)   pre2 = *(const float4*)(Ab + (size_t)(arow + 64) * LL + kn + aq * 4);
      if (r0 + arow + 96 < sl)   pre3 = *(const float4*)(Ab + (size_t)(arow + 96) * LL + kn + aq * 4);
    }
    __syncthreads();

    if (wave_active) {
      bf16x8 ah[2], al[2];
      #pragma unroll
      for (int mt = 0; mt < 2; ++mt) {
        const int row = w * 32 + mt * 16 + lr;
        ah[mt] = *(const bf16x8*)&Ahi[row][lk * 8];
        al[mt] = *(const bf16x8*)&Alo[row][lk * 8];
      }
      #pragma unroll
      for (int nt = 0; nt < 8; ++nt) {
        const int col = nt * 16 + lr;
        const bf16x8 bhf = *(const bf16x8*)&Bhi[col][lk * 8];
        const bf16x8 blf = *(const bf16x8*)&Blo[col][lk * 8];
        #pragma unroll
        for (int mt = 0; mt < 2; ++mt) {
          acc[mt][nt] = __builtin_amdgcn_mfma_f32_16x16x32_bf16(ah[mt], bhf, acc[mt][nt], 0, 0, 0);
          acc[mt][nt] = __builtin_amdgcn_mfma_f32_16x16x32_bf16(ah[mt], blf, acc[mt][nt], 0, 0, 0);
          acc[mt][nt] = __builtin_amdgcn_mfma_f32_16x16x32_bf16(al[mt], bhf, acc[mt][nt], 0, 0, 0);
        }
      }
    }
    __syncthreads();
  }

  #pragma unroll
  for (int mt = 0; mt < 2; ++mt)
    #pragma unroll
    for (int j = 0; j < 4; ++j) {
      const int row = r0 + w * 32 + mt * 16 + lk * 4 + j;
      if (row < sl) {
        float* dst = lowbuf + ((size_t)batch * SS + row) * HH;
        #pragma unroll
        for (int nt = 0; nt < 8; ++nt) dst[nt * 16 + lr] = acc[mt][nt][j];
      }
    }
}

// ========== Kernel 2: routing5 — low stays in L2, ~30KB LDS, 512 thr ==========
__global__ __launch_bounds__(512, 4) void routing5(
    const float* __restrict__ lowbuf, const int* __restrict__ seq_len,
    const float* __restrict__ r_init, float* __restrict__ out) {
  __shared__ __align__(16) float s_p[SS][KE];        //  8192
  __shared__ __align__(16) float s_part[4][KE][HH];  // 16384
  __shared__ __align__(16) float s_high[KE][HH];     //  4096
  __shared__ __align__(16) float s_inv[SS];          //  1024
  __shared__ __align__(16) float s_scale[KE];        //    32  => ~29.7 KB

  const int b = blockIdx.x, t = threadIdx.x, sl = seq_len[b];
  const int w = t >> 6, l = t & 63;

  const int ilog = 31 - __clz(sl);
  float nhf = ((sl & (sl - 1)) == 0) ? (float)ilog : log2f((float)sl);
  nhf = fmaxf(1.0f, fminf(16.0f, nhf));
  const int ka = (int)ceilf(nhf);

  const float* lowb = lowbuf + (size_t)b * SS * HH;

  // ---- s_p init ----
  #pragma unroll
  for (int m = 0; m < 4; ++m) {
    const int idx = m * 512 + t;
    const int s = idx >> 3, k = idx & 7;
    s_p[s][k] = r_init[((size_t)b * SS + s) * KMAX + k];
  }

  // ---- row inverse norms straight from L2 (2 thr/row) ----
  {
    const int s = t >> 1, hsub = t & 1;
    float n2 = 0.f;
    if (s < sl) {
      #pragma unroll
      for (int q = 0; q < 16; ++q) {
        const float4 v = *(const float4*)(lowb + (size_t)s * HH + hsub * 64 + q * 4);
        n2 = fmaf(v.x, v.x, fmaf(v.y, v.y, fmaf(v.z, v.z, fmaf(v.w, v.w, n2))));
      }
    }
    n2 += __shfl_xor(n2, 1, 64);
    if (hsub == 0 && s < sl) s_inv[s] = 1.0f / fmaxf(sqrtf(n2), 1e-12f);
  }
  __syncthreads();

  // phase-b decomposition: wave -> (g = s-quarter, ch = col-half); lane -> (rsub, cl)
  const int pb_g = w >> 1, pb_ch = w & 1;
  const int pb_rsub = l >> 4, pb_cl = l & 15;
  const int pb_h0 = pb_ch * 64 + pb_cl * 4;
  // phase-c decomposition: 2 thr/row
  const int pc_s = t >> 1, pc_hsub = t & 1;

  for (int it = 0; it < 3; ++it) {
    // (a) masked softmax over active k (zeroes p for s >= sl -- load-bearing!)
    if (t < SS) {
      const int s = t;
      const float4 ra = *(const float4*)&s_p[s][0];
      const float4 rb = *(const float4*)&s_p[s][4];
      float m = ra.x;
      if (1 < ka) m = fmaxf(m, ra.y);
      if (2 < ka) m = fmaxf(m, ra.z);
      if (3 < ka) m = fmaxf(m, ra.w);
      if (4 < ka) m = fmaxf(m, rb.x);
      if (5 < ka) m = fmaxf(m, rb.y);
      if (6 < ka) m = fmaxf(m, rb.z);
      if (7 < ka) m = fmaxf(m, rb.w);
      const float e0 = expf(ra.x - m);
      const float e1 = (1 < ka) ? expf(ra.y - m) : 0.f;
      const float e2 = (2 < ka) ? expf(ra.z - m) : 0.f;
      const float e3 = (3 < ka) ? expf(ra.w - m) : 0.f;
      const float e4 = (4 < ka) ? expf(rb.x - m) : 0.f;
      const float e5 = (5 < ka) ? expf(rb.y - m) : 0.f;
      const float e6 = (6 < ka) ? expf(rb.z - m) : 0.f;
      const float e7 = (7 < ka) ? expf(rb.w - m) : 0.f;
      const float sum = ((e0 + e1) + (e2 + e3)) + ((e4 + e5) + (e6 + e7));
      const float rs = (s < sl) ? (1.0f / sum) : 0.f;
      *(float4*)&s_p[s][0] = make_float4(e0 * rs, e1 * rs, e2 * rs, e3 * rs);
      *(float4*)&s_p[s][4] = make_float4(e4 * rs, e5 * rs, e6 * rs, e7 * rs);
    }
    __syncthreads();

    // (b) high[k][h] = sum_s low[s][h]*p[s][k]; each low elem read ONCE per iter
    {
      f32x4 acc0 = (f32x4){0,0,0,0}, acc1 = acc0, acc2 = acc0, acc3 = acc0;
      f32x4 acc4 = acc0, acc5 = acc0, acc6 = acc0, acc7 = acc0;
      for (int i = 0; i < 16; ++i) {
        const int s = pb_g * 64 + i * 4 + pb_rsub;
        if (s < sl) {
          const float4 v = *(const float4*)(lowb + (size_t)s * HH + pb_h0);
          const float4 pa = *(const float4*)&s_p[s][0];
          const float4 pb4 = *(const float4*)&s_p[s][4];
          acc0.x = fmaf(v.x, pa.x, acc0.x); acc0.y = fmaf(v.y, pa.x, acc0.y);
          acc0.z = fmaf(v.z, pa.x, acc0.z); acc0.w = fmaf(v.w, pa.x, acc0.w);
          acc1.x = fmaf(v.x, pa.y, acc1.x); acc1.y = fmaf(v.y, pa.y, acc1.y);
          acc1.z = fmaf(v.z, pa.y, acc1.z); acc1.w = fmaf(v.w, pa.y, acc1.w);
          acc2.x = fmaf(v.x, pa.z, acc2.x); acc2.y = fmaf(v.y, pa.z, acc2.y);
          acc2.z = fmaf(v.z, pa.z, acc2.z); acc2.w = fmaf(v.w, pa.z, acc2.w);
          acc3.x = fmaf(v.x, pa.w, acc3.x); acc3.y = fmaf(v.y, pa.w, acc3.y);
          acc3.z = fmaf(v.z, pa.w, acc3.z); acc3.w = fmaf(v.w, pa.w, acc3.w);
          acc4.x = fmaf(v.x, pb4.x, acc4.x); acc4.y = fmaf(v.y, pb4.x, acc4.y);
          acc4.z = fmaf(v.z, pb4.x, acc4.z); acc4.w = fmaf(v.w, pb4.x, acc4.w);
          acc5.x = fmaf(v.x, pb4.y, acc5.x); acc5.y = fmaf(v.y, pb4.y, acc5.y);
          acc5.z = fmaf(v.z, pb4.y, acc5.z); acc5.w = fmaf(v.w, pb4.y, acc5.w);
          acc6.x = fmaf(v.x, pb4.z, acc6.x); acc6.y = fmaf(v.y, pb4.z, acc6.y);
          acc6.z = fmaf(v.z, pb4.z, acc6.z); acc6.w = fmaf(v.w, pb4.z, acc6.w);
          acc7.x = fmaf(v.x, pb4.w, acc7.x); acc7.y = fmaf(v.y, pb4.w, acc7.y);
          acc7.z = fmaf(v.z, pb4.w, acc7.z); acc7.w = fmaf(v.w, pb4.w, acc7.w);
        }
      }
      // reduce over rsub (lane bits 4,5)
      #pragma unroll
      for (int c = 0; c < 4; ++c) {
        acc0[c] += __shfl_xor(acc0[c], 16, 64); acc0[c] += __shfl_xor(acc0[c], 32, 64);
        acc1[c] += __shfl_xor(acc1[c], 16, 64); acc1[c] += __shfl_xor(acc1[c], 32, 64);
        acc2[c] += __shfl_xor(acc2[c], 16, 64); acc2[c] += __shfl_xor(acc2[c], 32, 64);
        acc3[c] += __shfl_xor(acc3[c], 16, 64); acc3[c] += __shfl_xor(acc3[c], 32, 64);
        acc4[c] += __shfl_xor(acc4[c], 16, 64); acc4[c] += __shfl_xor(acc4[c], 32, 64);
        acc5[c] += __shfl_xor(acc5[c], 16, 64); acc5[c] += __shfl_xor(acc5[c], 32, 64);
        acc6[c] += __shfl_xor(acc6[c], 16, 64); acc6[c] += __shfl_xor(acc6[c], 32, 64);
        acc7[c] += __shfl_xor(acc7[c], 16, 64); acc7[c] += __shfl_xor(acc7[c], 32, 64);
      }
      if (pb_rsub == 0) {
        *(f32x4*)&s_part[pb_g][0][pb_h0] = acc0;
        *(f32x4*)&s_part[pb_g][1][pb_h0] = acc1;
        *(f32x4*)&s_part[pb_g][2][pb_h0] = acc2;
        *(f32x4*)&s_part[pb_g][3][pb_h0] = acc3;
        *(f32x4*)&s_part[pb_g][4][pb_h0] = acc4;
        *(f32x4*)&s_part[pb_g][5][pb_h0] = acc5;
        *(f32x4*)&s_part[pb_g][6][pb_h0] = acc6;
        *(f32x4*)&s_part[pb_g][7][pb_h0] = acc7;
      }
    }
    __syncthreads();
    #pragma unroll
    for (int m = 0; m < 2; ++m) {
      const int idx = m * 512 + t;
      const int k = idx >> 7, h = idx & 127;
      s_high[k][h] = (s_part[0][k][h] + s_part[1][k][h]) +
                     (s_part[2][k][h] + s_part[3][k][h]);
    }
    __syncthreads();

    // (c) r[s][k] += inv[s]*dot(high[k],low[s]); 2 thr/row, rows < sl only
    if (it < 2) {
      if (pc_s < sl) {
        float d0 = 0.f, d1 = 0.f, d2 = 0.f, d3 = 0.f;
        float d4 = 0.f, d5 = 0.f, d6 = 0.f, d7 = 0.f;
        #pragma unroll
        for (int q = 0; q < 16; ++q) {
          const int col = pc_hsub * 64 + q * 4;
          const float4 v = *(const float4*)(lowb + (size_t)pc_s * HH + col);
          const float4 h0 = *(const float4*)&s_high[0][col];
          const float4 h1 = *(const float4*)&s_high[1][col];
          const float4 h2 = *(const float4*)&s_high[2][col];
          const float4 h3 = *(const float4*)&s_high[3][col];
          const float4 h4 = *(const float4*)&s_high[4][col];
          const float4 h5 = *(const float4*)&s_high[5][col];
          const float4 h6 = *(const float4*)&s_high[6][col];
          const float4 h7 = *(const float4*)&s_high[7][col];
          d0 = fmaf(v.x, h0.x, fmaf(v.y, h0.y, fmaf(v.z, h0.z, fmaf(v.w, h0.w, d0))));
          d1 = fmaf(v.x, h1.x, fmaf(v.y, h1.y, fmaf(v.z, h1.z, fmaf(v.w, h1.w, d1))));
          d2 = fmaf(v.x, h2.x, fmaf(v.y, h2.y, fmaf(v.z, h2.z, fmaf(v.w, h2.w, d2))));
          d3 = fmaf(v.x, h3.x, fmaf(v.y, h3.y, fmaf(v.z, h3.z, fmaf(v.w, h3.w, d3))));
          d4 = fmaf(v.x, h4.x, fmaf(v.y, h4.y, fmaf(v.z, h4.z, fmaf(v.w, h4.w, d4))));
          d5 = fmaf(v.x, h5.x, fmaf(v.y, h5.y, fmaf(v.z, h5.z, fmaf(v.w, h5.w, d5))));
          d6 = fmaf(v.x, h6.x, fmaf(v.y, h6.y, fmaf(v.z, h6.z, fmaf(v.w, h6.w, d6))));
          d7 = fmaf(v.x, h7.x, fmaf(v.y, h7.y, fmaf(v.z, h7.z, fmaf(v.w, h7.w, d7))));
        }
        d0 += __shfl_xor(d0, 1, 64); d1 += __shfl_xor(d1, 1, 64);
        d2 += __shfl_xor(d2, 1, 64); d3 += __shfl_xor(d3, 1, 64);
        d4 += __shfl_xor(d4, 1, 64); d5 += __shfl_xor(d5, 1, 64);
        d6 += __shfl_xor(d6, 1, 64); d7 += __shfl_xor(d7, 1, 64);
        if (pc_hsub == 0) {
          const float inv = s_inv[pc_s];
          float4 p0 = *(const float4*)&s_p[pc_s][0];
          float4 p1 = *(const float4*)&s_p[pc_s][4];
          p0.x = fmaf(d0, inv, p0.x); p0.y = fmaf(d1, inv, p0.y);
          p0.z = fmaf(d2, inv, p0.z); p0.w = fmaf(d3, inv, p0.w);
          p1.x = fmaf(d4, inv, p1.x); p1.y = fmaf(d5, inv, p1.y);
          p1.z = fmaf(d6, inv, p1.z); p1.w = fmaf(d7, inv, p1.w);
          *(float4*)&s_p[pc_s][0] = p0;
          *(float4*)&s_p[pc_s][4] = p1;
        }
      } else {
        // keep shuffle structure defined for full wave (no-op values)
        float z = 0.f;
        z += __shfl_xor(z, 1, 64);
      }
      __syncthreads();
    } else {
      __syncthreads();
    }
  }

  // ---- squash ----
  if (t < 64) {
    const int k = t >> 3, part = t & 7;
    float n2 = 0.f;
    #pragma unroll
    for (int q = 0; q < 4; ++q) {
      const float4 v = *(const float4*)&s_high[k][part * 16 + q * 4];
      n2 = fmaf(v.x, v.x, fmaf(v.y, v.y, fmaf(v.z, v.z, fmaf(v.w, v.w, n2))));
    }
    n2 += __shfl_xor(n2, 1, 64);
    n2 += __shfl_xor(n2, 2, 64);
    n2 += __shfl_xor(n2, 4, 64);
    if (part == 0) {
      const float n = sqrtf(n2), ne = fmaxf(n, 1e-7f), sq = ne * ne;
      float sc = sq / ((1.0f + sq) * ne);
      if (k >= ka) sc = 0.f;
      s_scale[k] = sc;
    }
  }
  __syncthreads();
  {
    float* ob = out + (size_t)b * (KMAX * HH);
    #pragma unroll
    for (int m = 0; m < 2; ++m) {
      const int idx = m * 512 + t;
      const int k = idx >> 7, h = idx & 127;
      ob[k * HH + h]    = s_high[k][h] * s_scale[k];
      ob[KE * HH + idx] = 0.f;
    }
    if (t < KMAX)
      out[(size_t)NB * KMAX * HH + (size_t)b * KMAX + t] = (t < ka) ? 1.f : 0.f;
  }
}

// ===================== Fallback: round-3 fused kernel =======================
#define LOWPAD 132
__global__ __launch_bounds__(512) void capsule_fused(
    const float* __restrict__ inputs, const int* __restrict__ seq_len,
    const float* __restrict__ Wm, const float* __restrict__ r_init,
    float* __restrict__ out) {
  __shared__ __align__(16) float s_low[SS][LOWPAD];
  __shared__ __align__(16) float s_p[SS][KE];
  __shared__ __align__(16) float s_part[2][KE][HH];
  __shared__ __align__(16) float s_high[KE][HH];
  __shared__ __align__(16) float s_inv[SS];
  __shared__ __align__(16) float s_scale[KE];
  const int b = blockIdx.x, t = threadIdx.x, sl = seq_len[b];
  const int ilog = 31 - __clz(sl);
  float nh = ((sl & (sl - 1)) == 0) ? (float)ilog : log2f((float)sl);
  nh = fmaxf(1.0f, fminf(16.0f, nh));
  const int ka = (int)ceilf(nh);
  {
    const int hg = t & 15, h0 = hg * 8, rg = t >> 4;
    const float* inb = inputs + (size_t)b * SS * LL;
    for (int sweep = 0; sweep < 8; ++sweep) {
      const int s = sweep * 32 + rg;
      float a0=0.f,a1=0.f,a2=0.f,a3=0.f,a4=0.f,a5=0.f,a6=0.f,a7=0.f;
      if (s < sl) {
        const float* inp = inb + (size_t)s * LL;
        for (int ll = 0; ll < LL; ll += 4) {
          const float4 iv = *(const float4*)(inp + ll);
          #pragma unroll
          for (int d = 0; d < 4; ++d) {
            const float f = (d==0)?iv.x:(d==1)?iv.y:(d==2)?iv.z:iv.w;
            const float* wp = Wm + (size_t)(ll + d) * HH + h0;
            const float4 wa = *(const float4*)(wp);
            const float4 wb = *(const float4*)(wp + 4);
            a0=fmaf(f,wa.x,a0); a1=fmaf(f,wa.y,a1); a2=fmaf(f,wa.z,a2); a3=fmaf(f,wa.w,a3);
            a4=fmaf(f,wb.x,a4); a5=fmaf(f,wb.y,a5); a6=fmaf(f,wb.z,a6); a7=fmaf(f,wb.w,a7);
          }
        }
      }
      s_low[s][h0+0]=a0; s_low[s][h0+1]=a1; s_low[s][h0+2]=a2; s_low[s][h0+3]=a3;
      s_low[s][h0+4]=a4; s_low[s][h0+5]=a5; s_low[s][h0+6]=a6; s_low[s][h0+7]=a7;
    }
  }
  for (int idx = t; idx < SS * KE; idx += 512) {
    const int s = idx >> 3, k = idx & 7;
    s_p[s][k] = r_init[((size_t)b * SS + s) * KMAX + k];
  }
  __syncthreads();
  if (t < SS) {
    float n2 = 0.f;
    for (int h = 0; h < HH; ++h) { const float v = s_low[t][h]; n2 = fmaf(v, v, n2); }
    s_inv[t] = 1.0f / fmaxf(sqrtf(n2), 1e-12f);
  }
  __syncthreads();
  for (int it = 0; it < 3; ++it) {
    if (t < SS) {
      const int s = t;
      float rk0=s_p[s][0],rk1=s_p[s][1],rk2=s_p[s][2],rk3=s_p[s][3];
      float rk4=s_p[s][4],rk5=s_p[s][5],rk6=s_p[s][6],rk7=s_p[s][7];
      float m = rk0;
      if (1<ka) m=fmaxf(m,rk1); if (2<ka) m=fmaxf(m,rk2); if (3<ka) m=fmaxf(m,rk3);
      if (4<ka) m=fmaxf(m,rk4); if (5<ka) m=fmaxf(m,rk5); if (6<ka) m=fmaxf(m,rk6);
      if (7<ka) m=fmaxf(m,rk7);
      const float e0=expf(rk0-m);
      const float e1=(1<ka)?expf(rk1-m):0.f, e2=(2<ka)?expf(rk2-m):0.f;
      const float e3=(3<ka)?expf(rk3-m):0.f, e4=(4<ka)?expf(rk4-m):0.f;
      const float e5=(5<ka)?expf(rk5-m):0.f, e6=(6<ka)?expf(rk6-m):0.f;
      const float e7=(7<ka)?expf(rk7-m):0.f;
      const float sum=((e0+e1)+(e2+e3))+((e4+e5)+(e6+e7));
      const float rs=(s<sl)?(1.0f/sum):0.f;
      s_p[s][0]=e0*rs; s_p[s][1]=e1*rs; s_p[s][2]=e2*rs; s_p[s][3]=e3*rs;
      s_p[s][4]=e4*rs; s_p[s][5]=e5*rs; s_p[s][6]=e6*rs; s_p[s][7]=e7*rs;
    }
    __syncthreads();
    {
      const int g=t>>8, w4=(t>>6)&3, k=(t&63)>>3, hg=t&7, h0=w4*32+hg*4;
      float a0=0.f,a1=0.f,a2=0.f,a3=0.f;
      const int sbase=g*128;
      for (int i=0;i<128;++i) {
        const int s=sbase+i;
        const float4 v=*(const float4*)&s_low[s][h0];
        const float p=s_p[s][k];
        a0=fmaf(v.x,p,a0); a1=fmaf(v.y,p,a1); a2=fmaf(v.z,p,a2); a3=fmaf(v.w,p,a3);
      }
      s_part[g][k][h0+0]=a0; s_part[g][k][h0+1]=a1;
      s_part[g][k][h0+2]=a2; s_part[g][k][h0+3]=a3;
    }
    __syncthreads();
    for (int idx=t; idx<KE*HH; idx+=512) {
      const int k=idx>>7, h=idx&127;
      s_high[k][h]=s_part[0][k][h]+s_part[1][k][h];
    }
    __syncthreads();
    if (it < 2) {
      const int s=t&255, k0=(t>>8)<<2;
      float d0=0.f,d1=0.f,d2=0.f,d3=0.f;
      for (int h=0;h<HH;h+=4) {
        const float4 v=*(const float4*)&s_low[s][h];
        const float4 q0=*(const float4*)&s_high[k0+0][h];
        const float4 q1=*(const float4*)&s_high[k0+1][h];
        const float4 q2=*(const float4*)&s_high[k0+2][h];
        const float4 q3=*(const float4*)&s_high[k0+3][h];
        d0=fmaf(v.x,q0.x,fmaf(v.y,q0.y,fmaf(v.z,q0.z,fmaf(v.w,q0.w,d0))));
        d1=fmaf(v.x,q1.x,fmaf(v.y,q1.y,fmaf(v.z,q1.z,fmaf(v.w,q1.w,d1))));
        d2=fmaf(v.x,q2.x,fmaf(v.y,q2.y,fmaf(v.z,q2.z,fmaf(v.w,q2.w,d2))));
        d3=fmaf(v.x,q3.x,fmaf(v.y,q3.y,fmaf(v.z,q3.z,fmaf(v.w,q3.w,d3))));
      }
      const float inv=s_inv[s];
      s_p[s][k0+0]=fmaf(d0,inv,s_p[s][k0+0]);
      s_p[s][k0+1]=fmaf(d1,inv,s_p[s][k0+1]);
      s_p[s][k0+2]=fmaf(d2,inv,s_p[s][k0+2]);
      s_p[s][k0+3]=fmaf(d3,inv,s_p[s][k0+3]);
    }
    __syncthreads();
  }
  if (t < KE) {
    float n2=0.f;
    for (int h=0;h<HH;++h){ const float v=s_high[t][h]; n2=fmaf(v,v,n2); }
    const float n=sqrtf(n2), ne=fmaxf(n,1e-7f), sq=ne*ne;
    float sc=sq/((1.0f+sq)*ne);
    if (t>=ka) sc=0.f;
    s_scale[t]=sc;
  }
  __syncthreads();
  {
    const int w2=t>>6, lane=t&63;
    const float sc=s_scale[w2];
    float* ob=out+(size_t)b*(KMAX*HH);
    ob[w2*HH+lane]=s_high[w2][lane]*sc;
    ob[w2*HH+lane+64]=s_high[w2][lane+64]*sc;
    ob[KE*HH+t]=0.0f; ob[KE*HH+512+t]=0.0f;
    if (t<KMAX) {
      float* om=out+(size_t)NB*KMAX*HH;
      om[b*KMAX+t]=(t<ka)?1.0f:0.0f;
    }
  }
}

extern "C" void kernel_launch(void* const* d_in, const int* in_sizes, int n_in,
                              void* d_out, int out_size, void* d_ws, size_t ws_size,
                              hipStream_t stream) {
  const float* inputs  = (const float*)d_in[0];
  const int*   seq_len = (const int*)d_in[1];
  const float* Wm      = (const float*)d_in[2];
  const float* r_init  = (const float*)d_in[3];
  float* out           = (float*)d_out;
  const size_t low_bytes = (size_t)NB * SS * HH * sizeof(float);
  const size_t wt_bytes  = (size_t)HH * LL * sizeof(u16);
  if (ws_size >= low_bytes + 2 * wt_bytes) {
    float* lowbuf = (float*)d_ws;
    u16* wt_hi = (u16*)((char*)d_ws + low_bytes);
    u16* wt_lo = wt_hi + (size_t)HH * LL;
    hipLaunchKernelGGL(prep_w, dim3(128), dim3(256), 0, stream, Wm, wt_hi, wt_lo);
    hipLaunchKernelGGL(gemm_mfma, dim3(NB * 2), dim3(256), 0, stream,
                       inputs, seq_len, wt_hi, wt_lo, lowbuf);
    hipLaunchKernelGGL(routing5, dim3(NB), dim3(512), 0, stream,
                       lowbuf, seq_len, r_init, out);
  } else {
    hipLaunchKernelGGL(capsule_fused, dim3(NB), dim3(512), 0, stream,
                       inputs, seq_len, Wm, r_init, out);
  }
}

// Round 9
// 134.706 us; speedup vs baseline: 1.2464x; 1.2464x over previous
//
#include <hip/hip_runtime.h>
#include <hip/hip_bf16.h>

#define NB 1024
#define SS 256
#define LL 256
#define HH 128
#define KMAX 16
#define KE 8
#define LP 132

typedef __attribute__((ext_vector_type(8))) short bf16x8;
typedef __attribute__((ext_vector_type(4))) float f32x4;
typedef unsigned short u16;
typedef unsigned int u32;

__device__ __forceinline__ void split_bf16(float a, u16& hi, u16& lo) {
  u32 u = __float_as_uint(a);
  u32 hb = (u + 0x8000u) & 0xFFFF0000u;      // RTN-ish bf16 hi
  float lf = a - __uint_as_float(hb);        // exact residual
  hi = (u16)(hb >> 16);
  lo = (u16)(__float_as_uint(lf) >> 16);
}

// ---- prep: W[l][h] -> Wt_hi[h][l], Wt_lo[h][l] (bf16 split, transposed) ----
__global__ __launch_bounds__(256) void prep_w(
    const float* __restrict__ Wm, u16* __restrict__ wt_hi, u16* __restrict__ wt_lo) {
  const int id = blockIdx.x * 256 + threadIdx.x;
  const int h = id & 127, ll = id >> 7;
  const float a = Wm[(size_t)ll * HH + h];
  u16 hi, lo;
  split_bf16(a, hi, lo);
  wt_hi[h * LL + ll] = hi;
  wt_lo[h * LL + ll] = lo;
}

// =================== Fused kernel: GEMM(MFMA) + routing =====================
// 1 block = 1 batch. 512 threads (8 waves). s_low[256][132] fp32; its first
// 61440 B double as the GEMM staging buffers (dead by epilogue; barriers
// separate the aliased uses).
__global__ __launch_bounds__(512) void capsule_one(
    const float* __restrict__ inputs, const int* __restrict__ seq_len,
    const u16* __restrict__ wt_hi, const u16* __restrict__ wt_lo,
    const float* __restrict__ r_init, float* __restrict__ out) {
  __shared__ __align__(16) float s_low[SS][LP];      // 135168
  __shared__ __align__(16) float s_p[SS][KE];        //   8192
  __shared__ __align__(16) float s_part[2][KE][HH];  //   8192
  __shared__ __align__(16) float s_high[KE][HH];     //   4096
  __shared__ __align__(16) float s_inv[SS];          //   1024
  __shared__ __align__(16) float s_scale[KE];        //     32  => 156704 B

  const int b = blockIdx.x, t = threadIdx.x, sl = seq_len[b];
  const int w = t >> 6, l = t & 63, half = l >> 5, l31 = l & 31;

  const int ilog = 31 - __clz(sl);
  float nhf = ((sl & (sl - 1)) == 0) ? (float)ilog : log2f((float)sl);
  nhf = fmaxf(1.0f, fminf(16.0f, nhf));
  const int ka = (int)ceilf(nhf);

  // ---- s_p init (independent of GEMM; overlaps with A prefetch) ----
  #pragma unroll
  for (int m = 0; m < 4; ++m) {
    const int idx = m * 512 + t;
    s_p[idx >> 3][idx & 7] = r_init[((size_t)b * SS + (idx >> 3)) * KMAX + (idx & 7)];
  }

  // ---- GEMM phase: staging aliased over s_low[0..61440B) ----
  u16* Ahi = (u16*)&s_low[0][0];        // [256][40] u16 = 20480 B
  u16* Alo = Ahi + 256 * 40;            // 20480 B
  u16* Bhs = Alo + 256 * 40;            // [128][40] u16 = 10240 B
  u16* Bls = Bhs + 128 * 40;            // 10240 B  (total 61440 B)

  const int lr = l & 15, lk = l >> 4;
  f32x4 acc[2][8];
  #pragma unroll
  for (int mt = 0; mt < 2; ++mt)
    #pragma unroll
    for (int nt = 0; nt < 8; ++nt) acc[mt][nt] = (f32x4){0.f, 0.f, 0.f, 0.f};

  const float* Ab = inputs + (size_t)b * SS * LL;
  const int arow = t >> 3, aq = t & 7;           // A-stage: rows arow+{0,64,128,192}
  const int bcol = t >> 2, bpart = t & 3;        // B-stage: 16B per thread per buf
  const bool wave_active = (w * 32) < sl;

  float4 pre0, pre1, pre2, pre3;
  uint4 pbh, pbl;
  {
    if (arow < sl)        pre0 = *(const float4*)(Ab + (size_t)arow * LL + aq * 4);
    if (arow + 64 < sl)   pre1 = *(const float4*)(Ab + (size_t)(arow + 64) * LL + aq * 4);
    if (arow + 128 < sl)  pre2 = *(const float4*)(Ab + (size_t)(arow + 128) * LL + aq * 4);
    if (arow + 192 < sl)  pre3 = *(const float4*)(Ab + (size_t)(arow + 192) * LL + aq * 4);
    pbh = *(const uint4*)(wt_hi + (size_t)bcol * LL + bpart * 8);
    pbl = *(const uint4*)(wt_lo + (size_t)bcol * LL + bpart * 8);
  }

  for (int kc = 0; kc < LL; kc += 32) {
    // consume prefetched A: split -> LDS
    #pragma unroll
    for (int m = 0; m < 4; ++m) {
      const int row = arow + m * 64;
      const float4 v = (m == 0) ? pre0 : (m == 1) ? pre1 : (m == 2) ? pre2 : pre3;
      if (row < sl) {
        u16 h0,h1,h2,h3, l0,l1,l2,l3;
        split_bf16(v.x, h0, l0); split_bf16(v.y, h1, l1);
        split_bf16(v.z, h2, l2); split_bf16(v.w, h3, l3);
        uint2 hp, lp;
        hp.x = (u32)h0 | ((u32)h1 << 16);  hp.y = (u32)h2 | ((u32)h3 << 16);
        lp.x = (u32)l0 | ((u32)l1 << 16);  lp.y = (u32)l2 | ((u32)l3 << 16);
        *(uint2*)&Ahi[row * 40 + aq * 4] = hp;
        *(uint2*)&Alo[row * 40 + aq * 4] = lp;
      }
    }
    // consume prefetched B
    *(uint4*)&Bhs[bcol * 40 + bpart * 8] = pbh;
    *(uint4*)&Bls[bcol * 40 + bpart * 8] = pbl;
    // issue next-chunk loads (hide HBM/L2 latency under barrier + MFMA)
    if (kc + 32 < LL) {
      const int kn = kc + 32;
      if (arow < sl)        pre0 = *(const float4*)(Ab + (size_t)arow * LL + kn + aq * 4);
      if (arow + 64 < sl)   pre1 = *(const float4*)(Ab + (size_t)(arow + 64) * LL + kn + aq * 4);
      if (arow + 128 < sl)  pre2 = *(const float4*)(Ab + (size_t)(arow + 128) * LL + kn + aq * 4);
      if (arow + 192 < sl)  pre3 = *(const float4*)(Ab + (size_t)(arow + 192) * LL + kn + aq * 4);
      pbh = *(const uint4*)(wt_hi + (size_t)bcol * LL + kn + bpart * 8);
      pbl = *(const uint4*)(wt_lo + (size_t)bcol * LL + kn + bpart * 8);
    }
    __syncthreads();

    if (wave_active) {
      bf16x8 ah[2], al[2];
      #pragma unroll
      for (int mt = 0; mt < 2; ++mt) {
        const int row = w * 32 + mt * 16 + lr;
        ah[mt] = *(const bf16x8*)&Ahi[row * 40 + lk * 8];
        al[mt] = *(const bf16x8*)&Alo[row * 40 + lk * 8];
      }
      #pragma unroll
      for (int nt = 0; nt < 8; ++nt) {
        const int col = nt * 16 + lr;
        const bf16x8 bhf = *(const bf16x8*)&Bhs[col * 40 + lk * 8];
        const bf16x8 blf = *(const bf16x8*)&Bls[col * 40 + lk * 8];
        #pragma unroll
        for (int mt = 0; mt < 2; ++mt) {
          acc[mt][nt] = __builtin_amdgcn_mfma_f32_16x16x32_bf16(ah[mt], bhf, acc[mt][nt], 0, 0, 0);
          acc[mt][nt] = __builtin_amdgcn_mfma_f32_16x16x32_bf16(ah[mt], blf, acc[mt][nt], 0, 0, 0);
          acc[mt][nt] = __builtin_amdgcn_mfma_f32_16x16x32_bf16(al[mt], bhf, acc[mt][nt], 0, 0, 0);
        }
      }
    }
    __syncthreads();   // also fences staging before epilogue overwrites it
  }

  // ---- epilogue: acc -> s_low fp32 (rows >= sl forced to exact 0) ----
  #pragma unroll
  for (int mt = 0; mt < 2; ++mt)
    #pragma unroll
    for (int j = 0; j < 4; ++j) {
      const int row = w * 32 + mt * 16 + lk * 4 + j;
      const bool live = row < sl;
      #pragma unroll
      for (int nt = 0; nt < 8; ++nt)
        s_low[row][nt * 16 + lr] = live ? acc[mt][nt][j] : 0.f;
    }
  __syncthreads();

  // ---- row inverse norms (routing3 pattern) ----
  {
    const int s = w * 32 + l31;
    float n2 = 0.f;
    #pragma unroll
    for (int q = 0; q < 16; ++q) {
      const float4 v = *(const float4*)&s_low[s][half * 64 + q * 4];
      n2 = fmaf(v.x, v.x, fmaf(v.y, v.y, fmaf(v.z, v.z, fmaf(v.w, v.w, n2))));
    }
    n2 += __shfl_xor(n2, 32, 64);
    if (half == 0) s_inv[s] = 1.0f / fmaxf(sqrtf(n2), 1e-12f);
  }
  __syncthreads();

  for (int it = 0; it < 3; ++it) {
    // (a) masked softmax
    if (t < SS) {
      const int s = t;
      const float4 ra = *(const float4*)&s_p[s][0];
      const float4 rb = *(const float4*)&s_p[s][4];
      float m = ra.x;
      if (1 < ka) m = fmaxf(m, ra.y);
      if (2 < ka) m = fmaxf(m, ra.z);
      if (3 < ka) m = fmaxf(m, ra.w);
      if (4 < ka) m = fmaxf(m, rb.x);
      if (5 < ka) m = fmaxf(m, rb.y);
      if (6 < ka) m = fmaxf(m, rb.z);
      if (7 < ka) m = fmaxf(m, rb.w);
      const float e0 = expf(ra.x - m);
      const float e1 = (1 < ka) ? expf(ra.y - m) : 0.f;
      const float e2 = (2 < ka) ? expf(ra.z - m) : 0.f;
      const float e3 = (3 < ka) ? expf(ra.w - m) : 0.f;
      const float e4 = (4 < ka) ? expf(rb.x - m) : 0.f;
      const float e5 = (5 < ka) ? expf(rb.y - m) : 0.f;
      const float e6 = (6 < ka) ? expf(rb.z - m) : 0.f;
      const float e7 = (7 < ka) ? expf(rb.w - m) : 0.f;
      const float sum = ((e0 + e1) + (e2 + e3)) + ((e4 + e5) + (e6 + e7));
      const float rs = (s < sl) ? (1.0f / sum) : 0.f;
      *(float4*)&s_p[s][0] = make_float4(e0 * rs, e1 * rs, e2 * rs, e3 * rs);
      *(float4*)&s_p[s][4] = make_float4(e4 * rs, e5 * rs, e6 * rs, e7 * rs);
    }
    __syncthreads();

    // (b) high partials: 8 waves = (g: s-half, kq: k-pair); sl-trimmed
    {
      const int g = w >> 2, kq = w & 3, k0 = kq * 2;
      const int slg = min(128, max(0, sl - g * 128));
      const int ni = (slg + 1) >> 1;
      float a0x = 0.f, a0y = 0.f, a0z = 0.f, a0w = 0.f;
      float a1x = 0.f, a1y = 0.f, a1z = 0.f, a1w = 0.f;
      for (int i = 0; i < ni; ++i) {
        const int s = g * 128 + i * 2 + half;
        const float4 v = *(const float4*)&s_low[s][l31 * 4];
        const float2 p2 = *(const float2*)&s_p[s][k0];
        a0x = fmaf(v.x, p2.x, a0x); a0y = fmaf(v.y, p2.x, a0y);
        a0z = fmaf(v.z, p2.x, a0z); a0w = fmaf(v.w, p2.x, a0w);
        a1x = fmaf(v.x, p2.y, a1x); a1y = fmaf(v.y, p2.y, a1y);
        a1z = fmaf(v.z, p2.y, a1z); a1w = fmaf(v.w, p2.y, a1w);
      }
      a0x += __shfl_xor(a0x, 32, 64); a0y += __shfl_xor(a0y, 32, 64);
      a0z += __shfl_xor(a0z, 32, 64); a0w += __shfl_xor(a0w, 32, 64);
      a1x += __shfl_xor(a1x, 32, 64); a1y += __shfl_xor(a1y, 32, 64);
      a1z += __shfl_xor(a1z, 32, 64); a1w += __shfl_xor(a1w, 32, 64);
      if (half == 0) {
        *(float4*)&s_part[g][k0][l31 * 4]     = make_float4(a0x, a0y, a0z, a0w);
        *(float4*)&s_part[g][k0 + 1][l31 * 4] = make_float4(a1x, a1y, a1z, a1w);
      }
    }
    __syncthreads();
    #pragma unroll
    for (int m = 0; m < 2; ++m) {
      const int idx = m * 512 + t;
      const int k = idx >> 7, h = idx & 127;
      s_high[k][h] = s_part[0][k][h] + s_part[1][k][h];
    }
    __syncthreads();

    // (c) r[s][k] += inv[s]*dot(high[k],low[s]); skip rows >= sl
    if (it < 2) {
      const int s = w * 32 + l31;
      if (s < sl) {
        float d0 = 0.f, d1 = 0.f, d2 = 0.f, d3 = 0.f;
        float d4 = 0.f, d5 = 0.f, d6 = 0.f, d7 = 0.f;
        #pragma unroll
        for (int q = 0; q < 16; ++q) {
          const int h = half * 64 + q * 4;
          const float4 v = *(const float4*)&s_low[s][h];
          const float4 h0 = *(const float4*)&s_high[0][h];
          const float4 h1 = *(const float4*)&s_high[1][h];
          const float4 h2 = *(const float4*)&s_high[2][h];
          const float4 h3 = *(const float4*)&s_high[3][h];
          const float4 h4 = *(const float4*)&s_high[4][h];
          const float4 h5 = *(const float4*)&s_high[5][h];
          const float4 h6 = *(const float4*)&s_high[6][h];
          const float4 h7 = *(const float4*)&s_high[7][h];
          d0 = fmaf(v.x, h0.x, fmaf(v.y, h0.y, fmaf(v.z, h0.z, fmaf(v.w, h0.w, d0))));
          d1 = fmaf(v.x, h1.x, fmaf(v.y, h1.y, fmaf(v.z, h1.z, fmaf(v.w, h1.w, d1))));
          d2 = fmaf(v.x, h2.x, fmaf(v.y, h2.y, fmaf(v.z, h2.z, fmaf(v.w, h2.w, d2))));
          d3 = fmaf(v.x, h3.x, fmaf(v.y, h3.y, fmaf(v.z, h3.z, fmaf(v.w, h3.w, d3))));
          d4 = fmaf(v.x, h4.x, fmaf(v.y, h4.y, fmaf(v.z, h4.z, fmaf(v.w, h4.w, d4))));
          d5 = fmaf(v.x, h5.x, fmaf(v.y, h5.y, fmaf(v.z, h5.z, fmaf(v.w, h5.w, d5))));
          d6 = fmaf(v.x, h6.x, fmaf(v.y, h6.y, fmaf(v.z, h6.z, fmaf(v.w, h6.w, d6))));
          d7 = fmaf(v.x, h7.x, fmaf(v.y, h7.y, fmaf(v.z, h7.z, fmaf(v.w, h7.w, d7))));
        }
        d0 += __shfl_xor(d0, 32, 64); d1 += __shfl_xor(d1, 32, 64);
        d2 += __shfl_xor(d2, 32, 64); d3 += __shfl_xor(d3, 32, 64);
        d4 += __shfl_xor(d4, 32, 64); d5 += __shfl_xor(d5, 32, 64);
        d6 += __shfl_xor(d6, 32, 64); d7 += __shfl_xor(d7, 32, 64);
        if (half == 0) {
          const float inv = s_inv[s];
          float4 p0 = *(const float4*)&s_p[s][0];
          float4 p1 = *(const float4*)&s_p[s][4];
          p0.x = fmaf(d0, inv, p0.x); p0.y = fmaf(d1, inv, p0.y);
          p0.z = fmaf(d2, inv, p0.z); p0.w = fmaf(d3, inv, p0.w);
          p1.x = fmaf(d4, inv, p1.x); p1.y = fmaf(d5, inv, p1.y);
          p1.z = fmaf(d6, inv, p1.z); p1.w = fmaf(d7, inv, p1.w);
          *(float4*)&s_p[s][0] = p0;
          *(float4*)&s_p[s][4] = p1;
        }
      }
    }
    __syncthreads();
  }

  // ---- squash + output ----
  if (t < 64) {
    const int k = t >> 3, part = t & 7;
    float n2 = 0.f;
    #pragma unroll
    for (int q = 0; q < 4; ++q) {
      const float4 v = *(const float4*)&s_high[k][part * 16 + q * 4];
      n2 = fmaf(v.x, v.x, fmaf(v.y, v.y, fmaf(v.z, v.z, fmaf(v.w, v.w, n2))));
    }
    n2 += __shfl_xor(n2, 1, 64);
    n2 += __shfl_xor(n2, 2, 64);
    n2 += __shfl_xor(n2, 4, 64);
    if (part == 0) {
      const float n = sqrtf(n2), ne = fmaxf(n, 1e-7f), sq = ne * ne;
      float sc = sq / ((1.0f + sq) * ne);
      if (k >= ka) sc = 0.f;
      s_scale[k] = sc;
    }
  }
  __syncthreads();
  {
    float* ob = out + (size_t)b * (KMAX * HH);
    #pragma unroll
    for (int m = 0; m < 2; ++m) {
      const int idx = m * 512 + t;
      const int k = idx >> 7, h = idx & 127;
      ob[k * HH + h]    = s_high[k][h] * s_scale[k];
      ob[KE * HH + idx] = 0.f;
    }
    if (t < KMAX)
      out[(size_t)NB * KMAX * HH + (size_t)b * KMAX + t] = (t < ka) ? 1.f : 0.f;
  }
}

// ===================== Fallback: round-3 fused kernel =======================
#define LOWPAD 132
__global__ __launch_bounds__(512) void capsule_fused(
    const float* __restrict__ inputs, const int* __restrict__ seq_len,
    const float* __restrict__ Wm, const float* __restrict__ r_init,
    float* __restrict__ out) {
  __shared__ __align__(16) float s_low[SS][LOWPAD];
  __shared__ __align__(16) float s_p[SS][KE];
  __shared__ __align__(16) float s_part[2][KE][HH];
  __shared__ __align__(16) float s_high[KE][HH];
  __shared__ __align__(16) float s_inv[SS];
  __shared__ __align__(16) float s_scale[KE];
  const int b = blockIdx.x, t = threadIdx.x, sl = seq_len[b];
  const int ilog = 31 - __clz(sl);
  float nh = ((sl & (sl - 1)) == 0) ? (float)ilog : log2f((float)sl);
  nh = fmaxf(1.0f, fminf(16.0f, nh));
  const int ka = (int)ceilf(nh);
  {
    const int hg = t & 15, h0 = hg * 8, rg = t >> 4;
    const float* inb = inputs + (size_t)b * SS * LL;
    for (int sweep = 0; sweep < 8; ++sweep) {
      const int s = sweep * 32 + rg;
      float a0=0.f,a1=0.f,a2=0.f,a3=0.f,a4=0.f,a5=0.f,a6=0.f,a7=0.f;
      if (s < sl) {
        const float* inp = inb + (size_t)s * LL;
        for (int ll = 0; ll < LL; ll += 4) {
          const float4 iv = *(const float4*)(inp + ll);
          #pragma unroll
          for (int d = 0; d < 4; ++d) {
            const float f = (d==0)?iv.x:(d==1)?iv.y:(d==2)?iv.z:iv.w;
            const float* wp = Wm + (size_t)(ll + d) * HH + h0;
            const float4 wa = *(const float4*)(wp);
            const float4 wb = *(const float4*)(wp + 4);
            a0=fmaf(f,wa.x,a0); a1=fmaf(f,wa.y,a1); a2=fmaf(f,wa.z,a2); a3=fmaf(f,wa.w,a3);
            a4=fmaf(f,wb.x,a4); a5=fmaf(f,wb.y,a5); a6=fmaf(f,wb.z,a6); a7=fmaf(f,wb.w,a7);
          }
        }
      }
      s_low[s][h0+0]=a0; s_low[s][h0+1]=a1; s_low[s][h0+2]=a2; s_low[s][h0+3]=a3;
      s_low[s][h0+4]=a4; s_low[s][h0+5]=a5; s_low[s][h0+6]=a6; s_low[s][h0+7]=a7;
    }
  }
  for (int idx = t; idx < SS * KE; idx += 512) {
    const int s = idx >> 3, k = idx & 7;
    s_p[s][k] = r_init[((size_t)b * SS + s) * KMAX + k];
  }
  __syncthreads();
  if (t < SS) {
    float n2 = 0.f;
    for (int h = 0; h < HH; ++h) { const float v = s_low[t][h]; n2 = fmaf(v, v, n2); }
    s_inv[t] = 1.0f / fmaxf(sqrtf(n2), 1e-12f);
  }
  __syncthreads();
  for (int it = 0; it < 3; ++it) {
    if (t < SS) {
      const int s = t;
      float rk0=s_p[s][0],rk1=s_p[s][1],rk2=s_p[s][2],rk3=s_p[s][3];
      float rk4=s_p[s][4],rk5=s_p[s][5],rk6=s_p[s][6],rk7=s_p[s][7];
      float m = rk0;
      if (1<ka) m=fmaxf(m,rk1); if (2<ka) m=fmaxf(m,rk2); if (3<ka) m=fmaxf(m,rk3);
      if (4<ka) m=fmaxf(m,rk4); if (5<ka) m=fmaxf(m,rk5); if (6<ka) m=fmaxf(m,rk6);
      if (7<ka) m=fmaxf(m,rk7);
      const float e0=expf(rk0-m);
      const float e1=(1<ka)?expf(rk1-m):0.f, e2=(2<ka)?expf(rk2-m):0.f;
      const float e3=(3<ka)?expf(rk3-m):0.f, e4=(4<ka)?expf(rk4-m):0.f;
      const float e5=(5<ka)?expf(rk5-m):0.f, e6=(6<ka)?expf(rk6-m):0.f;
      const float e7=(7<ka)?expf(rk7-m):0.f;
      const float sum=((e0+e1)+(e2+e3))+((e4+e5)+(e6+e7));
      const float rs=(s<sl)?(1.0f/sum):0.f;
      s_p[s][0]=e0*rs; s_p[s][1]=e1*rs; s_p[s][2]=e2*rs; s_p[s][3]=e3*rs;
      s_p[s][4]=e4*rs; s_p[s][5]=e5*rs; s_p[s][6]=e6*rs; s_p[s][7]=e7*rs;
    }
    __syncthreads();
    {
      const int g=t>>8, w4=(t>>6)&3, k=(t&63)>>3, hg=t&7, h0=w4*32+hg*4;
      float a0=0.f,a1=0.f,a2=0.f,a3=0.f;
      const int sbase=g*128;
      for (int i=0;i<128;++i) {
        const int s=sbase+i;
        const float4 v=*(const float4*)&s_low[s][h0];
        const float p=s_p[s][k];
        a0=fmaf(v.x,p,a0); a1=fmaf(v.y,p,a1); a2=fmaf(v.z,p,a2); a3=fmaf(v.w,p,a3);
      }
      s_part[g][k][h0+0]=a0; s_part[g][k][h0+1]=a1;
      s_part[g][k][h0+2]=a2; s_part[g][k][h0+3]=a3;
    }
    __syncthreads();
    for (int idx=t; idx<KE*HH; idx+=512) {
      const int k=idx>>7, h=idx&127;
      s_high[k][h]=s_part[0][k][h]+s_part[1][k][h];
    }
    __syncthreads();
    if (it < 2) {
      const int s=t&255, k0=(t>>8)<<2;
      float d0=0.f,d1=0.f,d2=0.f,d3=0.f;
      for (int h=0;h<HH;h+=4) {
        const float4 v=*(const float4*)&s_low[s][h];
        const float4 q0=*(const float4*)&s_high[k0+0][h];
        const float4 q1=*(const float4*)&s_high[k0+1][h];
        const float4 q2=*(const float4*)&s_high[k0+2][h];
        const float4 q3=*(const float4*)&s_high[k0+3][h];
        d0=fmaf(v.x,q0.x,fmaf(v.y,q0.y,fmaf(v.z,q0.z,fmaf(v.w,q0.w,d0))));
        d1=fmaf(v.x,q1.x,fmaf(v.y,q1.y,fmaf(v.z,q1.z,fmaf(v.w,q1.w,d1))));
        d2=fmaf(v.x,q2.x,fmaf(v.y,q2.y,fmaf(v.z,q2.z,fmaf(v.w,q2.w,d2))));
        d3=fmaf(v.x,q3.x,fmaf(v.y,q3.y,fmaf(v.z,q3.z,fmaf(v.w,q3.w,d3))));
      }
      const float inv=s_inv[s];
      s_p[s][k0+0]=fmaf(d0,inv,s_p[s][k0+0]);
      s_p[s][k0+1]=fmaf(d1,inv,s_p[s][k0+1]);
      s_p[s][k0+2]=fmaf(d2,inv,s_p[s][k0+2]);
      s_p[s][k0+3]=fmaf(d3,inv,s_p[s][k0+3]);
    }
    __syncthreads();
  }
  if (t < KE) {
    float n2=0.f;
    for (int h=0;h<HH;++h){ const float v=s_high[t][h]; n2=fmaf(v,v,n2); }
    const float n=sqrtf(n2), ne=fmaxf(n,1e-7f), sq=ne*ne;
    float sc=sq/((1.0f+sq)*ne);
    if (t>=ka) sc=0.f;
    s_scale[t]=sc;
  }
  __syncthreads();
  {
    const int w2=t>>6, lane=t&63;
    const float sc=s_scale[w2];
    float* ob=out+(size_t)b*(KMAX*HH);
    ob[w2*HH+lane]=s_high[w2][lane]*sc;
    ob[w2*HH+lane+64]=s_high[w2][lane+64]*sc;
    ob[KE*HH+t]=0.0f; ob[KE*HH+512+t]=0.0f;
    if (t<KMAX) {
      float* om=out+(size_t)NB*KMAX*HH;
      om[b*KMAX+t]=(t<ka)?1.0f:0.0f;
    }
  }
}

extern "C" void kernel_launch(void* const* d_in, const int* in_sizes, int n_in,
                              void* d_out, int out_size, void* d_ws, size_t ws_size,
                              hipStream_t stream) {
  const float* inputs  = (const float*)d_in[0];
  const int*   seq_len = (const int*)d_in[1];
  const float* Wm      = (const float*)d_in[2];
  const float* r_init  = (const float*)d_in[3];
  float* out           = (float*)d_out;
  const size_t wt_bytes = (size_t)HH * LL * sizeof(u16);   // 64 KB each
  if (ws_size >= 2 * wt_bytes) {
    u16* wt_hi = (u16*)d_ws;
    u16* wt_lo = wt_hi + (size_t)HH * LL;
    hipLaunchKernelGGL(prep_w, dim3(128), dim3(256), 0, stream, Wm, wt_hi, wt_lo);
    hipLaunchKernelGGL(capsule_one, dim3(NB), dim3(512), 0, stream,
                       inputs, seq_len, wt_hi, wt_lo, r_init, out);
  } else {
    hipLaunchKernelGGL(capsule_fused, dim3(NB), dim3(512), 0, stream,
                       inputs, seq_len, Wm, r_init, out);
  }
}